// Round 12
// baseline (316.172 us; speedup 1.0000x reference)
//
#include <hip/hip_runtime.h>
#include <hip/hip_bf16.h>

typedef __hip_bfloat16 bf16;
typedef __attribute__((ext_vector_type(8))) short short8;   // 8 bf16
typedef __attribute__((ext_vector_type(4))) short short4v;  // 4 bf16
typedef __attribute__((ext_vector_type(4))) float f32x4;
typedef __attribute__((ext_vector_type(4))) int i32x4;

#define N_ 32768
#define D_ 256
#define S_ 256
#define B_ 128
#define E_ 524288

static __device__ __forceinline__ f32x4 mfma16(short8 a, short8 b, f32x4 c) {
  return __builtin_amdgcn_mfma_f32_16x16x32_bf16(a, b, c, 0, 0, 0);
}
static __device__ __forceinline__ f32x4 fzero4() {
  f32x4 z; z[0] = 0.f; z[1] = 0.f; z[2] = 0.f; z[3] = 0.f; return z;
}
static __device__ __forceinline__ float bits2f(short s) {
  unsigned u = ((unsigned)(unsigned short)s) << 16;
  return __builtin_bit_cast(float, u);
}
static __device__ __forceinline__ short f2bits(float f) {
  bf16 b = __float2bfloat16(f);
  return __builtin_bit_cast(short, b);
}

#define GLOAD_LDS16(G, L) __builtin_amdgcn_global_load_lds( \
    (const __attribute__((address_space(1))) void*)(G),     \
    (__attribute__((address_space(3))) void*)(L), 16, 0, 0)

// ---------------------------------------------------------------------------
// bf16 MFMA GEMM, 128x128 tile, BK=32, double-buffered LDS (R9, no setprio).
// Flags: 1=relu, 2=bias, 4=resid f32, 8=out f32, 16=out bf16, 32=colstats,
//        64=resid bf16, 128=dual bias (biasB for cols>=256).
// ---------------------------------------------------------------------------
template<int F>
__global__ __launch_bounds__(256)
void gemm_bt(const bf16* __restrict__ A, const bf16* __restrict__ Bt,
             const float* __restrict__ bias, const float* __restrict__ biasB,
             const void* __restrict__ resid,
             float* __restrict__ Cf, bf16* __restrict__ Cb,
             float* __restrict__ Sp, float* __restrict__ SSp,
             int M, int Nc, int K, long bsA, long bsB, long bsC)
{
  __shared__ __align__(16) bf16 lA[2 * 128 * 32];
  __shared__ __align__(16) bf16 lB[2 * 128 * 32];
  __shared__ float sS[2][128], sSS[2][128];
  const int z = blockIdx.z;
  const bf16* Ab = A + (long)z * bsA;
  const bf16* Bb = Bt + (long)z * bsB;
  const int m0 = blockIdx.x * 128, n0 = blockIdx.y * 128;
  const int tid = threadIdx.x;
  const int lane = tid & 63;
  const int w = tid >> 6, wr = w >> 1, wc = w & 1;
  const int g = lane >> 4, r = lane & 15, ko = g * 8;
  const int srow = lane >> 2, skw = (lane & 3) * 8;

  f32x4 acc[4][4];
  for (int i = 0; i < 4; i++) for (int j = 0; j < 4; j++) acc[i][j] = fzero4();

  for (int i = 0; i < 2; i++) {
    const int c = w * 2 + i;
    GLOAD_LDS16(Ab + (long)(m0 + c * 16 + srow) * K + skw, lA + c * 512);
    GLOAD_LDS16(Bb + (long)(n0 + c * 16 + srow) * K + skw, lB + c * 512);
  }
  __syncthreads();

  for (int k0 = 0; k0 < K; k0 += 32) {
    const int cur = (k0 >> 5) & 1, nxt = cur ^ 1;
    if (k0 + 32 < K) {
      for (int i = 0; i < 2; i++) {
        const int c = w * 2 + i;
        GLOAD_LDS16(Ab + (long)(m0 + c * 16 + srow) * K + (k0 + 32) + skw,
                    lA + nxt * 4096 + c * 512);
        GLOAD_LDS16(Bb + (long)(n0 + c * 16 + srow) * K + (k0 + 32) + skw,
                    lB + nxt * 4096 + c * 512);
      }
    }
    short8 af[4], bfv[4];
    for (int mi = 0; mi < 4; mi++)
      af[mi] = *(const short8*)&lA[cur * 4096 + (wr * 64 + mi * 16 + r) * 32 + ko];
    for (int ni = 0; ni < 4; ni++)
      bfv[ni] = *(const short8*)&lB[cur * 4096 + (wc * 64 + ni * 16 + r) * 32 + ko];
    for (int mi = 0; mi < 4; mi++)
      for (int ni = 0; ni < 4; ni++)
        acc[mi][ni] = mfma16(af[mi], bfv[ni], acc[mi][ni]);
    __syncthreads();   // drains vmcnt(0): next buffer ready; guards cur reuse
  }

  float cs[4] = {0, 0, 0, 0}, css[4] = {0, 0, 0, 0};
  for (int mi = 0; mi < 4; mi++) for (int ni = 0; ni < 4; ni++) {
    const int row = m0 + wr * 64 + mi * 16 + g * 4;
    const int col = n0 + wc * 64 + ni * 16 + r;
    float bv = 0.0f;
    if (F & 2) {
      if ((F & 128) && col >= 256) bv = biasB[col - 256];
      else bv = bias[col];
    }
    for (int j = 0; j < 4; j++) {
      long idx = (long)(row + j) * Nc + col;
      float v = acc[mi][ni][j] + bv;
      if (F & 4)  v += ((const float*)resid)[(long)z * bsC + idx];
      if (F & 64) v += bits2f(((const short*)resid)[(long)z * bsC + idx]);
      if (F & 1)  v = fmaxf(v, 0.0f);
      if (F & 32) { cs[ni] += v; css[ni] += v * v; }
      if (F & 8)  Cf[(long)z * bsC + idx] = v;
      if (F & 16) Cb[(long)z * bsC + idx] = __float2bfloat16(v);
    }
  }
  if (F & 32) {
    for (int ni = 0; ni < 4; ni++) {
      cs[ni]  += __shfl_xor(cs[ni], 16);  cs[ni]  += __shfl_xor(cs[ni], 32);
      css[ni] += __shfl_xor(css[ni], 16); css[ni] += __shfl_xor(css[ni], 32);
    }
    if (lane < 16) {
      for (int ni = 0; ni < 4; ni++) {
        sS[wr][wc * 64 + ni * 16 + lane]  = cs[ni];
        sSS[wr][wc * 64 + ni * 16 + lane] = css[ni];
      }
    }
    __syncthreads();
    if (tid < 128) {
      atomicAdd(&Sp[n0 + tid],  sS[0][tid] + sS[1][tid]);
      atomicAdd(&SSp[n0 + tid], sSS[0][tid] + sSS[1][tid]);
    }
  }
}

// ---------------------------------------------------------------------------
// Generalized fused MLP-chain body, 512 threads / 8 waves, dbuf (R9, no
// setprio). Block = 64 rows, widths 256. Stage 1: A(global) @ B1 -> lC
// (XOR-swizzled LDS). Stages 2..NS read lC.
// EP1 bits: 1=bias 2=relu 4=resid(bf16).  EP2 bits: 1=bias 2=relu.
// ---------------------------------------------------------------------------
template<int NS, int EP1, int EP2, bool STATS>
static __device__ __forceinline__ void mlp_body(
    const bf16* __restrict__ A, const bf16* __restrict__ B1,
    const bf16* __restrict__ B2, const bf16* __restrict__ B3,
    const float* __restrict__ bEp1, const float* __restrict__ bEp2,
    const float* __restrict__ bFin, const bf16* __restrict__ resid,
    bf16* __restrict__ out, float* __restrict__ Sp, float* __restrict__ SSp,
    bf16* lA, bf16* lB, bf16* lC)
{
  char* lCc = (char*)lC;
  const int tid = threadIdx.x;          // 512 threads
  const int lane = tid & 63;
  const int w = tid >> 6;               // 8 waves: mh = w>>2, nq = w&3
  const int mh = w >> 2, nq = w & 3;
  const int g = lane >> 4, r = lane & 15, ko = g * 8;

  f32x4 acc[2][4];
  for (int i = 0; i < 2; i++) for (int j = 0; j < 4; j++) acc[i][j] = fzero4();

  // ---- stage 1: acc = A @ B1 (dbuf) ----
  if (tid < 256)
    GLOAD_LDS16(A + (long)(tid >> 2) * 256 + (tid & 3) * 8, lA + w * 512);
  GLOAD_LDS16(B1 + (long)(tid >> 2) * 256 + (tid & 3) * 8, lB + w * 512);
  GLOAD_LDS16(B1 + (long)((tid + 512) >> 2) * 256 + ((tid + 512) & 3) * 8,
              lB + w * 512 + 4096);
  __syncthreads();
  for (int k0 = 0; k0 < 256; k0 += 32) {
    const int cur = (k0 >> 5) & 1, nxt = cur ^ 1;
    if (k0 + 32 < 256) {
      if (tid < 256)
        GLOAD_LDS16(A + (long)(tid >> 2) * 256 + (k0 + 32) + (tid & 3) * 8,
                    lA + nxt * 2048 + w * 512);
      GLOAD_LDS16(B1 + (long)(tid >> 2) * 256 + (k0 + 32) + (tid & 3) * 8,
                  lB + nxt * 8192 + w * 512);
      GLOAD_LDS16(B1 + (long)((tid + 512) >> 2) * 256 + (k0 + 32) + ((tid + 512) & 3) * 8,
                  lB + nxt * 8192 + w * 512 + 4096);
    }
    short8 af[2], bfv[4];
    for (int mi = 0; mi < 2; mi++)
      af[mi] = *(const short8*)&lA[cur * 2048 + (mh * 32 + mi * 16 + r) * 32 + ko];
    for (int ni = 0; ni < 4; ni++)
      bfv[ni] = *(const short8*)&lB[cur * 8192 + (nq * 64 + ni * 16 + r) * 32 + ko];
    for (int mi = 0; mi < 2; mi++)
      for (int ni = 0; ni < 4; ni++)
        acc[mi][ni] = mfma16(af[mi], bfv[ni], acc[mi][ni]);
    __syncthreads();
  }
  // epilogue 1 -> lC (swizzled)
  for (int mi = 0; mi < 2; mi++) for (int ni = 0; ni < 4; ni++) {
    const int col = nq * 64 + ni * 16 + r;
    const float bv = (EP1 & 1) ? bEp1[col] : 0.0f;
    for (int j = 0; j < 4; j++) {
      const int row = mh * 32 + mi * 16 + g * 4 + j;
      float v = acc[mi][ni][j] + bv;
      if (EP1 & 4) v += bits2f(__builtin_bit_cast(short, resid[(long)row * 256 + col]));
      if (EP1 & 2) v = fmaxf(v, 0.0f);
      *(short*)(lCc + ((row * 512 + col * 2) ^ ((row & 7) << 4))) = f2bits(v);
    }
  }
  __syncthreads();

  // ---- stages 2..NS: acc = lC @ Bs (dbuf lB) ----
  for (int s = 2; s <= NS; s++) {
    const bf16* Bs = (s == 2) ? B2 : B3;
    for (int i = 0; i < 2; i++) for (int j = 0; j < 4; j++) acc[i][j] = fzero4();
    GLOAD_LDS16(Bs + (long)(tid >> 2) * 256 + (tid & 3) * 8, lB + w * 512);
    GLOAD_LDS16(Bs + (long)((tid + 512) >> 2) * 256 + ((tid + 512) & 3) * 8,
                lB + w * 512 + 4096);
    __syncthreads();
    for (int k0 = 0; k0 < 256; k0 += 32) {
      const int cur = (k0 >> 5) & 1, nxt = cur ^ 1;
      if (k0 + 32 < 256) {
        GLOAD_LDS16(Bs + (long)(tid >> 2) * 256 + (k0 + 32) + (tid & 3) * 8,
                    lB + nxt * 8192 + w * 512);
        GLOAD_LDS16(Bs + (long)((tid + 512) >> 2) * 256 + (k0 + 32) + ((tid + 512) & 3) * 8,
                    lB + nxt * 8192 + w * 512 + 4096);
      }
      short8 af[2], bfv[4];
      for (int mi = 0; mi < 2; mi++) {
        const int row = mh * 32 + mi * 16 + r;
        af[mi] = *(const short8*)(lCc +
                  ((row * 512 + (k0 + ko) * 2) ^ ((row & 7) << 4)));
      }
      for (int ni = 0; ni < 4; ni++)
        bfv[ni] = *(const short8*)&lB[cur * 8192 + (nq * 64 + ni * 16 + r) * 32 + ko];
      for (int mi = 0; mi < 2; mi++)
        for (int ni = 0; ni < 4; ni++)
          acc[mi][ni] = mfma16(af[mi], bfv[ni], acc[mi][ni]);
      __syncthreads();
    }
    if (s < NS) {
      for (int mi = 0; mi < 2; mi++) for (int ni = 0; ni < 4; ni++) {
        const int col = nq * 64 + ni * 16 + r;
        const float bv = (EP2 & 1) ? bEp2[col] : 0.0f;
        for (int j = 0; j < 4; j++) {
          const int row = mh * 32 + mi * 16 + g * 4 + j;
          float v = acc[mi][ni][j] + bv;
          if (EP2 & 2) v = fmaxf(v, 0.0f);
          *(short*)(lCc + ((row * 512 + col * 2) ^ ((row & 7) << 4))) = f2bits(v);
        }
      }
      __syncthreads();
    }
  }

  // ---- final epilogue ----
  float cs[4] = {0, 0, 0, 0}, css[4] = {0, 0, 0, 0};
  for (int mi = 0; mi < 2; mi++) for (int ni = 0; ni < 4; ni++) {
    const int col = nq * 64 + ni * 16 + r;
    const float bv = bFin[col];
    for (int j = 0; j < 4; j++) {
      const int row = mh * 32 + mi * 16 + g * 4 + j;
      float v = acc[mi][ni][j] + bv;
      if (STATS) { cs[ni] += v; css[ni] += v * v; }
      out[(long)row * 256 + col] = __float2bfloat16(v);
    }
  }
  if (STATS) {
    for (int ni = 0; ni < 4; ni++) {
      cs[ni]  += __shfl_xor(cs[ni], 16);  cs[ni]  += __shfl_xor(cs[ni], 32);
      css[ni] += __shfl_xor(css[ni], 16); css[ni] += __shfl_xor(css[ni], 32);
    }
    __syncthreads();
    float* sS = (float*)lC;
    if (lane < 16) {
      for (int ni = 0; ni < 4; ni++) {
        sS[mh * 256 + nq * 64 + ni * 16 + lane] = cs[ni];
        sS[512 + mh * 256 + nq * 64 + ni * 16 + lane] = css[ni];
      }
    }
    __syncthreads();
    if (tid < 256) {
      atomicAdd(&Sp[tid],  sS[tid] + sS[256 + tid]);
      atomicAdd(&SSp[tid], sS[512 + tid] + sS[768 + tid]);
    }
  }
}

// One launch: GCN expert (blocks 0-511), GIN expert (512-1023), Q-chain
// (1024-1535).
__global__ __launch_bounds__(512)
void fused3_k(const bf16* __restrict__ adjGCNb, const bf16* __restrict__ adjGINb,
              const bf16* __restrict__ xT, const bf16* __restrict__ xb,
              const bf16* __restrict__ WgcnT, const bf16* __restrict__ Wgin1T,
              const bf16* __restrict__ Wgin2T, const bf16* __restrict__ Wq1T,
              const bf16* __restrict__ Wq2T, const bf16* __restrict__ WqaT,
              const float* __restrict__ b_gcn, const float* __restrict__ b_gin1,
              const float* __restrict__ b_gin2, const float* __restrict__ bq1,
              const float* __restrict__ bq2, const float* __restrict__ bq_a,
              bf16* __restrict__ hgcnb, bf16* __restrict__ hginb,
              bf16* __restrict__ qhb,
              float* __restrict__ S0, float* __restrict__ SS0,
              float* __restrict__ S1, float* __restrict__ SS1)
{
  __shared__ __align__(16) bf16 lA[2 * 64 * 32];     // 8 KB dbuf
  __shared__ __align__(16) bf16 lB[2 * 256 * 32];    // 32 KB dbuf
  __shared__ __align__(16) bf16 lC[64 * 256];        // 32 KB
  const int bid = blockIdx.x;
  if (bid < 512) {
    const long g = bid >> 2;
    mlp_body<2, 0, 0, true>(adjGCNb + (long)bid * 16384, xT + g * 65536,
        WgcnT, nullptr, nullptr, nullptr, b_gcn, nullptr,
        hgcnb + (long)bid * 16384, S0, SS0, lA, lB, lC);
  } else if (bid < 1024) {
    const int sub = bid - 512;
    const long g = sub >> 2;
    mlp_body<3, 4, 3, true>(adjGINb + (long)sub * 16384, xT + g * 65536,
        Wgin1T, Wgin2T, nullptr, b_gin1, b_gin2, xb + (long)sub * 16384,
        hginb + (long)sub * 16384, S1, SS1, lA, lB, lC);
  } else {
    const int sub = bid - 1024;
    mlp_body<3, 3, 1, false>(xb + (long)sub * 16384, Wq1T, Wq2T, WqaT,
        bq1, bq2, bq_a, nullptr, qhb + (long)sub * 16384, nullptr, nullptr,
        lA, lB, lC);
  }
}

// ---------------------------------------------------------------------------
// Fused attention, swapped-QK^T (exact R9 version: q-half grid, paired-u32
// V-staging, setprio around MFMA clusters).
// ---------------------------------------------------------------------------
__global__ __launch_bounds__(256, 2)
void attn_k(const bf16* __restrict__ qh, const bf16* __restrict__ kh,
            const bf16* __restrict__ vh, bf16* __restrict__ ob, int ks)
{
  const int h = blockIdx.x, qhf = blockIdx.y, b = blockIdx.z;
  const int tid = threadIdx.x, lane = tid & 63, w = tid >> 6;
  const int g = lane >> 4, r = lane & 15, ko = g * 8;
  __shared__ __align__(16) bf16 lK[256 * 32];
  __shared__ __align__(16) bf16 lV[32 * 256];
  char* lKc = (char*)lK;
  char* lVc = (char*)lV;

  for (int i = 0; i < 4; i++) {
    int c = tid + i * 256;
    int row = c >> 2, p4 = c & 3;
    short8 v = *(const short8*)(kh + (long)(b * 256 + row) * ks + h * 32 + p4 * 8);
    *(short8*)(lKc + ((row * 64 + p4 * 16) ^ ((row & 7) << 4))) = v;
  }
  for (int i = 0; i < 2; i++) {
    int c = tid + i * 256;
    int sp = c >> 2, part = c & 3;
    const bf16* vp = vh + (long)(b * 256 + 2 * sp) * ks + h * 32 + part * 8;
    short8 va = *(const short8*)(vp);
    short8 vb = *(const short8*)(vp + ks);
    #pragma unroll
    for (int j = 0; j < 8; j++) {
      int dh = part * 8 + j;
      int sw = ((dh & 7) ^ ((dh >> 3) << 1)) & 7;
      unsigned wrd = ((unsigned)(unsigned short)vb[j] << 16) |
                     (unsigned)(unsigned short)va[j];
      *(unsigned*)(lVc + ((dh * 512 + sp * 4) ^ (sw << 4))) = wrd;
    }
  }
  __syncthreads();

  const float c1 = 0.17677669529663687f * 1.4426950408889634f;
  const int idx0 = (((lane >> 4) & 1) * 32 + r) * 4;
  const int idx1 = idx0 + 64;
  const bool selhi = lane >= 32;

  for (int mc = 0; mc < 2; mc++) {
    const long qbase = (long)b * 256 + qhf * 128 + w * 32 + mc * 16;
    short8 qf = *(const short8*)(qh + (qbase + r) * 256 + h * 32 + ko);
    f32x4 sc[16];
    __builtin_amdgcn_s_setprio(1);
    #pragma unroll
    for (int nc = 0; nc < 16; nc++) {
      int row = nc * 16 + r;
      short8 kf = *(const short8*)(lKc + ((row * 64 + g * 16) ^ ((r & 7) << 4)));
      sc[nc] = mfma16(kf, qf, fzero4());
    }
    __builtin_amdgcn_s_setprio(0);
    f32x4 m4 = sc[0];
    #pragma unroll
    for (int nc = 1; nc < 16; nc++)
      for (int j = 0; j < 4; j++) m4[j] = fmaxf(m4[j], sc[nc][j]);
    float mx = fmaxf(fmaxf(m4[0], m4[1]), fmaxf(m4[2], m4[3]));
    mx = fmaxf(mx, __shfl_xor(mx, 16));
    mx = fmaxf(mx, __shfl_xor(mx, 32));
    const float mxc = mx * c1;
    f32x4 s4 = fzero4();
    #pragma unroll
    for (int nc = 0; nc < 16; nc++)
      for (int j = 0; j < 4; j++) {
        float p = exp2f(fmaf(sc[nc][j], c1, -mxc));
        sc[nc][j] = p; s4[j] += p;
      }
    float sum = s4[0] + s4[1] + s4[2] + s4[3];
    sum += __shfl_xor(sum, 16);
    sum += __shfl_xor(sum, 32);
    const float invs = 1.0f / sum;
    f32x4 oa[2]; oa[0] = fzero4(); oa[1] = fzero4();
    __builtin_amdgcn_s_setprio(1);
    #pragma unroll
    for (int kc = 0; kc < 8; kc++) {
      int pkA0, pkA1, pkB0, pkB1;
      {
        const f32x4 pa = sc[2 * kc], pb = sc[2 * kc + 1];
        unsigned a0 = (unsigned short)f2bits(pa[0] * invs);
        unsigned a1 = (unsigned short)f2bits(pa[1] * invs);
        unsigned a2 = (unsigned short)f2bits(pa[2] * invs);
        unsigned a3 = (unsigned short)f2bits(pa[3] * invs);
        unsigned b0 = (unsigned short)f2bits(pb[0] * invs);
        unsigned b1 = (unsigned short)f2bits(pb[1] * invs);
        unsigned b2 = (unsigned short)f2bits(pb[2] * invs);
        unsigned b3 = (unsigned short)f2bits(pb[3] * invs);
        pkA0 = (int)((a1 << 16) | a0);
        pkA1 = (int)((a3 << 16) | a2);
        pkB0 = (int)((b1 << 16) | b0);
        pkB1 = (int)((b3 << 16) | b2);
      }
      int A0 = __builtin_amdgcn_ds_bpermute(idx0, pkA0);
      int A1 = __builtin_amdgcn_ds_bpermute(idx0, pkA1);
      int B0 = __builtin_amdgcn_ds_bpermute(idx0, pkB0);
      int B1 = __builtin_amdgcn_ds_bpermute(idx0, pkB1);
      int C0 = __builtin_amdgcn_ds_bpermute(idx1, pkA0);
      int C1 = __builtin_amdgcn_ds_bpermute(idx1, pkA1);
      int D0 = __builtin_amdgcn_ds_bpermute(idx1, pkB0);
      int D1 = __builtin_amdgcn_ds_bpermute(idx1, pkB1);
      i32x4 av;
      av[0] = selhi ? B0 : A0;
      av[1] = selhi ? B1 : A1;
      av[2] = selhi ? D0 : C0;
      av[3] = selhi ? D1 : C1;
      short8 af = __builtin_bit_cast(short8, av);
      #pragma unroll
      for (int n = 0; n < 2; n++) {
        int dh = n * 16 + r;
        int sw = ((dh & 7) ^ ((dh >> 3) << 1)) & 7;
        short8 bv = *(const short8*)(lVc + ((dh * 512 + kc * 64 + g * 16) ^ (sw << 4)));
        oa[n] = mfma16(af, bv, oa[n]);
      }
    }
    __builtin_amdgcn_s_setprio(0);
    #pragma unroll
    for (int n = 0; n < 2; n++)
      for (int j = 0; j < 4; j++)
        ob[(qbase + g * 4 + j) * 256 + h * 32 + n * 16 + r] =
          __float2bfloat16(oa[n][j]);
  }
}

// ---------------------------------------------------------------------------
// Merged preamble: blocks 0-831 weight transposes; 832-9023 xprep (x -> xb +
// per-graph xT); 9024-11071 edge_cnt. All independent.
// ---------------------------------------------------------------------------
__global__ __launch_bounds__(256)
void prep_k(const float* w0, const float* w1, const float* w2, const float* w3,
            const float* w4, const float* w5, const float* w6, const float* w7,
            const float* w8, const float* wf1, const float* wf2,
            bf16* __restrict__ wT,
            const float* __restrict__ x, bf16* __restrict__ xb,
            bf16* __restrict__ xT,
            const int* __restrict__ ei, unsigned* __restrict__ cnt)
{
  __shared__ float tile[32][33];
  const int bid = blockIdx.x;
  const int tid = threadIdx.x;
  const int tx = tid & 31, ty = tid >> 5;

  if (bid < 832) {                 // ---- weight transposes ----
    const float* srcs[9] = {w0, w1, w2, w3, w4, w5, w6, w7, w8};
    const float* in; bf16* out; int in_rs, out_rs, bx, by;
    if (bid < 576) {
      int wi = bid >> 6, t = bid & 63;
      in = srcs[wi]; out = wT + (long)wi * 65536;
      in_rs = 256; out_rs = 256; bx = t & 7; by = t >> 3;
    } else if (bid < 704) {
      int t = bid - 576;
      in = wf1; out = wT + 589824;
      in_rs = 512; out_rs = 256; bx = t & 15; by = t >> 4;
    } else {
      int t = bid - 704;
      in = wf2; out = wT + 720896;
      in_rs = 256; out_rs = 512; bx = t & 7; by = t >> 3;
    }
    const int c = bx * 32 + tx;
    const int rb = by * 32;
    for (int i = 0; i < 4; i++)
      tile[ty + i * 8][tx] = in[(long)(rb + ty + i * 8) * in_rs + c];
    __syncthreads();
    const int oc = rb + tx;
    const int orb = bx * 32;
    for (int i = 0; i < 4; i++)
      out[(long)(orb + ty + i * 8) * out_rs + oc] =
        __float2bfloat16(tile[tx][ty + i * 8]);
  } else if (bid < 9024) {         // ---- xprep ----
    const int b2 = bid - 832;
    const int z = b2 >> 6, bx = b2 & 7, by = (b2 >> 3) & 7;
    const long ioff = (long)z * 65536;
    const int c = bx * 32 + tx;
    const int rb = by * 32;
    for (int i = 0; i < 4; i++) {
      float v = x[ioff + (long)(rb + ty + i * 8) * 256 + c];
      tile[ty + i * 8][tx] = v;
      xb[ioff + (long)(rb + ty + i * 8) * 256 + c] = __float2bfloat16(v);
    }
    __syncthreads();
    const int oc = rb + tx;
    const int orb = bx * 32;
    for (int i = 0; i < 4; i++)
      xT[ioff + (long)(orb + ty + i * 8) * 256 + oc] =
        __float2bfloat16(tile[tx][ty + i * 8]);
  } else {                         // ---- edge_cnt ----
    int e = (bid - 9024) * 256 + tid;
    int src = ei[e], dst = ei[E_ + e];
    long idx = ((long)(src >> 8) * 256 + (dst & 255)) * 256 + (src & 255);
    atomicAdd(&cnt[idx >> 2], 1u << ((idx & 3) * 8));
  }
}

// ---------------------------------------------------------------------------
// Graph derive: one block per graph. deg (row sums, dinv in LDS) + both
// bf16 adjacencies, in one pass over the u8 counts.
// ---------------------------------------------------------------------------
__global__ __launch_bounds__(256)
void graph_prep_k(const unsigned* __restrict__ cnt,
                  bf16* __restrict__ gin, bf16* __restrict__ gcn)
{
  __shared__ float sdinv[256];
  const int gg = blockIdx.x, tid = threadIdx.x;
  const unsigned* cg = cnt + (long)gg * 16384;   // 16384 u32 words per graph
  const int l16 = tid & 15, rg = tid >> 4;
  for (int p = 0; p < 16; p++) {
    const int row = p * 16 + rg;
    uint4 v = ((const uint4*)(cg + (long)row * 64))[l16];
    unsigned s = 0;
    s += (v.x & 0xFF) + ((v.x >> 8) & 0xFF) + ((v.x >> 16) & 0xFF) + (v.x >> 24);
    s += (v.y & 0xFF) + ((v.y >> 8) & 0xFF) + ((v.y >> 16) & 0xFF) + (v.y >> 24);
    s += (v.z & 0xFF) + ((v.z >> 8) & 0xFF) + ((v.z >> 16) & 0xFF) + (v.z >> 24);
    s += (v.w & 0xFF) + ((v.w >> 8) & 0xFF) + ((v.w >> 16) & 0xFF) + (v.w >> 24);
    s += __shfl_xor(s, 1); s += __shfl_xor(s, 2);
    s += __shfl_xor(s, 4); s += __shfl_xor(s, 8);
    if (l16 == 0) sdinv[row] = rsqrtf((float)s + 1.0f);
  }
  __syncthreads();
  for (int p = 0; p < 64; p++) {
    const int wl = p * 256 + tid;        // word within graph
    const unsigned cw = cg[wl];
    const long i = ((long)gg * 16384 + wl) * 4;  // global cell index
    const int cell = wl * 4;
    const int dst = cell >> 8, src0 = cell & 255;
    const float dd = sdinv[dst];
    float cv[4] = {(float)(cw & 0xFF), (float)((cw >> 8) & 0xFF),
                   (float)((cw >> 16) & 0xFF), (float)(cw >> 24)};
    short4v oi, oc;
    for (int j = 0; j < 4; j++) {
      float gv = cv[j] * dd * sdinv[src0 + j];
      if (src0 + j == dst) gv += dd * dd;
      oi[j] = f2bits(cv[j]);
      oc[j] = f2bits(gv);
    }
    *(short4v*)(gin + i) = oi;
    *(short4v*)(gcn + i) = oc;
  }
}

// BN(e0),BN(e1) stats -> global mean/std(ddof=1) -> mix coefficients
__global__ __launch_bounds__(256)
void expert_stats_k(const float* __restrict__ S0, const float* __restrict__ SS0,
                    const float* __restrict__ S1, const float* __restrict__ SS1,
                    const float* __restrict__ gkv, const float* __restrict__ bkv,
                    float* __restrict__ kA, float* __restrict__ kB,
                    float* __restrict__ kC)
{
  const int d = threadIdx.x;
  const float invN = 1.0f / 32768.0f;
  float m0 = S0[d] * invN, v0 = SS0[d] * invN - m0 * m0;
  float a0 = gkv[d] * rsqrtf(v0 + 1e-5f), c0 = bkv[d] - m0 * a0;
  float m1 = S1[d] * invN, v1 = SS1[d] * invN - m1 * m1;
  float a1 = gkv[d] * rsqrtf(v1 + 1e-5f), c1 = bkv[d] - m1 * a1;
  float gsum = a0 * S0[d] + 32768.0f * c0 + a1 * S1[d] + 32768.0f * c1;
  float gss  = a0 * a0 * SS0[d] + 2.0f * a0 * c0 * S0[d] + 32768.0f * c0 * c0
             + a1 * a1 * SS1[d] + 2.0f * a1 * c1 * S1[d] + 32768.0f * c1 * c1;
  __shared__ float r1[256], r2[256];
  r1[d] = gsum; r2[d] = gss;
  __syncthreads();
  for (int s = 128; s > 0; s >>= 1) {
    if (d < s) { r1[d] += r1[d + s]; r2[d] += r2[d + s]; }
    __syncthreads();
  }
  const float cntall = 16777216.0f;  // 2*N*D
  float tg = r1[0], tss = r2[0];
  float gm = tg / cntall;
  float var = (tss - tg * tg / cntall) / (cntall - 1.0f);
  float gs = sqrtf(fmaxf(var, 0.f)) + 1e-8f;
  kA[d] = 0.5f * a0 / gs;
  kB[d] = 0.5f * a1 / gs;
  kC[d] = 0.5f * (c0 + c1 - 2.0f * gm) / gs;
}

__global__ __launch_bounds__(256)
void kv_mix_k(const bf16* __restrict__ hgcn, const bf16* __restrict__ hgin,
              const bf16* __restrict__ xb, const float* __restrict__ kA,
              const float* __restrict__ kB, const float* __restrict__ kC,
              bf16* __restrict__ kv)
{
  long i = ((long)blockIdx.x * 256 + threadIdx.x) * 8;
  int d0 = (int)(i & 255);
  short8 a = *(const short8*)(hgcn + i);
  short8 b = *(const short8*)(hgin + i);
  short8 c = *(const short8*)(xb + i);
  short8 o;
  for (int j = 0; j < 8; j++) {
    int d = d0 + j;
    float v = kA[d] * bits2f(a[j]) + kB[d] * bits2f(b[j]) + kC[d] + 0.1f * bits2f(c[j]);
    o[j] = f2bits(v);
  }
  *(short8*)(kv + i) = o;
}

// MODE: 1 = write f32, 2 = write bf16
template<int MODE>
__global__ __launch_bounds__(256)
void bn_apply_k(const bf16* __restrict__ in, const float* __restrict__ S,
                const float* __restrict__ SSq, const float* __restrict__ gg,
                const float* __restrict__ bb, float* __restrict__ outf,
                bf16* __restrict__ outb)
{
  long i = ((long)blockIdx.x * 256 + threadIdx.x) * 8;
  int d0 = (int)(i & 255);
  short8 v = *(const short8*)(in + i);
  const float invN = 1.0f / 32768.0f;
  float4 o0, o1; short8 o8;
  for (int j = 0; j < 8; j++) {
    int d = d0 + j;
    float m = S[d] * invN;
    float var = SSq[d] * invN - m * m;
    float a = gg[d] * rsqrtf(var + 1e-5f);
    float c = bb[d] - m * a;
    float o = a * bits2f(v[j]) + c;
    if (MODE & 1) { if (j < 4) (&o0.x)[j] = o; else (&o1.x)[j - 4] = o; }
    if (MODE & 2) o8[j] = f2bits(o);
  }
  if (MODE & 1) { *(float4*)(outf + i) = o0; *(float4*)(outf + i + 4) = o1; }
  if (MODE & 2) *(short8*)(outb + i) = o8;
}

// ---------------------------------------------------------------------------
// Workspace layout (bytes). qhb lives in the dead counts slot (16.7MB);
// tbufb/t2b reuse it after attn.
// ---------------------------------------------------------------------------
static constexpr size_t OFF_S0 = 0, OFF_SS0 = 1024, OFF_S1 = 2048, OFF_SS1 = 3072;
static constexpr size_t OFF_S2 = 4096, OFF_SS2 = 5120, OFF_S3 = 6144, OFF_SS3 = 7168;
static constexpr size_t OFF_KA = 8192, OFF_KB = 9216, OFF_KC = 10240;
static constexpr size_t OFF_CNT = 16384;                       // u8 counts -> qhb -> tbufb
static constexpr size_t CNT_BYTES = (size_t)B_ * S_ * S_;      // 8388608
static constexpr size_t ZERO_BYTES = OFF_CNT + CNT_BYTES;
static constexpr size_t OFF_DINV = OFF_CNT + (size_t)B_ * S_ * S_ * 2;
static constexpr size_t OFF_W = OFF_DINV + 131072;
static constexpr size_t NDB2 = (size_t)N_ * D_ * 2;            // 16777216
static constexpr size_t OFF_ADJGINB = OFF_W + 1703936;   // adjGIN -> f1b(lo)
static constexpr size_t OFF_ADJGCNB = OFF_ADJGINB + NDB2; // adjGCN -> f1b(hi)
static constexpr size_t OFF_XB   = OFF_ADJGCNB + NDB2;    // xb -> hb
static constexpr size_t OFF_XT   = OFF_XB + NDB2;         // xT
static constexpr size_t OFF_AGG  = OFF_XT + NDB2;         // khvb(lo)
static constexpr size_t OFF_GIN  = OFF_AGG + NDB2;        // khvb(hi)
static constexpr size_t OFF_KV   = OFF_GIN + NDB2;        // kv
static constexpr size_t OFF_HGCN = OFF_KV + NDB2;         // hgcn
static constexpr size_t OFF_HGIN = OFF_HGCN + NDB2;       // hgin -> ob

extern "C" void kernel_launch(void* const* d_in, const int* in_sizes, int n_in,
                              void* d_out, int out_size, void* d_ws, size_t ws_size,
                              hipStream_t stream)
{
  (void)in_sizes; (void)n_in; (void)out_size; (void)ws_size;
  const float* x      = (const float*)d_in[0];
  const int*   ei     = (const int*)d_in[1];
  const float* W_gcn  = (const float*)d_in[2];
  const float* b_gcn  = (const float*)d_in[3];
  const float* W_gin1 = (const float*)d_in[4];
  const float* b_gin1 = (const float*)d_in[5];
  const float* W_gin2 = (const float*)d_in[6];
  const float* b_gin2 = (const float*)d_in[7];
  const float* g_kv   = (const float*)d_in[8];
  const float* be_kv  = (const float*)d_in[9];
  const float* Wq1    = (const float*)d_in[10];
  const float* bq1    = (const float*)d_in[11];
  const float* Wq2    = (const float*)d_in[12];
  const float* bq2    = (const float*)d_in[13];
  const float* Wq_a   = (const float*)d_in[14];
  const float* bq_a   = (const float*)d_in[15];
  const float* Wk_a   = (const float*)d_in[16];
  const float* bk_a   = (const float*)d_in[17];
  const float* Wv_a   = (const float*)d_in[18];
  const float* bv_a   = (const float*)d_in[19];
  const float* Wo_a   = (const float*)d_in[20];
  const float* bo_a   = (const float*)d_in[21];
  const float* g_attn = (const float*)d_in[22];
  const float* be_attn= (const float*)d_in[23];
  const float* Wf1    = (const float*)d_in[24];
  const float* bf1    = (const float*)d_in[25];
  const float* Wf2    = (const float*)d_in[26];
  const float* bf2    = (const float*)d_in[27];
  const float* g2     = (const float*)d_in[28];
  const float* be2    = (const float*)d_in[29];

  char* ws = (char*)d_ws;
  float* S0  = (float*)(ws + OFF_S0);  float* SS0 = (float*)(ws + OFF_SS0);
  float* S1  = (float*)(ws + OFF_S1);  float* SS1 = (float*)(ws + OFF_SS1);
  float* S2  = (float*)(ws + OFF_S2);  float* SS2 = (float*)(ws + OFF_SS2);
  float* S3  = (float*)(ws + OFF_S3);  float* SS3 = (float*)(ws + OFF_SS3);
  float* kA  = (float*)(ws + OFF_KA);  float* kB  = (float*)(ws + OFF_KB);
  float* kC  = (float*)(ws + OFF_KC);
  unsigned* cntA = (unsigned*)(ws + OFF_CNT);
  bf16* wT = (bf16*)(ws + OFF_W);
  bf16 *WgcnT = wT,            *Wgin1T = wT + 65536,  *Wgin2T = wT + 131072;
  bf16 *Wq1T  = wT + 196608,   *Wq2T   = wT + 262144, *WqaT   = wT + 327680;
  bf16 *WkaT  = wT + 393216,   *WoaT   = wT + 524288;
  bf16 *Wf1T  = wT + 589824,   *Wf2T   = wT + 720896;
  bf16* adjGINb = (bf16*)(ws + OFF_ADJGINB);
  bf16* adjGCNb = (bf16*)(ws + OFF_ADJGCNB);
  bf16* xb    = (bf16*)(ws + OFF_XB);
  bf16* xT    = (bf16*)(ws + OFF_XT);
  bf16* kv_bf = (bf16*)(ws + OFF_KV);
  bf16* hgcnb = (bf16*)(ws + OFF_HGCN);
  bf16* hginb = (bf16*)(ws + OFF_HGIN);
  // lifetime-disjoint aliases
  bf16* qhb    = (bf16*)(ws + OFF_CNT);    // counts dead after graph_prep
  bf16* khvb   = (bf16*)(ws + OFF_AGG);    // [N][512], spans AGG+GIN
  bf16* ob     = hginb;                    // after kv_mix consumed hgin
  bf16* tbufb  = (bf16*)(ws + OFF_CNT);    // after attn consumed qhb
  bf16* hb     = xb;                       // after o-GEMM consumed xb resid
  bf16* f1b    = adjGINb;                  // spans ADJGIN+ADJGCN (33.5MB)
  bf16* t2b    = (bf16*)(ws + OFF_CNT);    // after bn_apply<2> consumed tbufb
  float* outp  = (float*)d_out;

  hipMemsetAsync(d_ws, 0, ZERO_BYTES, stream);

  // merged preamble: weights + x-prep + edge counting, one launch
  prep_k<<<11072, 256, 0, stream>>>(W_gcn, W_gin1, W_gin2, Wq1, Wq2,
      Wq_a, Wk_a, Wv_a, Wo_a, Wf1, Wf2, wT, x, xb, xT, ei, cntA);
  // deg + adjacency derivation, one block per graph (dinv in LDS)
  graph_prep_k<<<128, 256, 0, stream>>>(cntA, adjGINb, adjGCNb);
  // GCN expert + GIN expert + Q-chain in ONE launch (512-thread, dbuf)
  fused3_k<<<1536, 512, 0, stream>>>(adjGCNb, adjGINb, xT, xb,
      WgcnT, Wgin1T, Wgin2T, Wq1T, Wq2T, WqaT,
      b_gcn, b_gin1, b_gin2, bq1, bq2, bq_a,
      hgcnb, hginb, qhb, S0, SS0, S1, SS1);
  expert_stats_k<<<1, 256, 0, stream>>>(S0, SS0, S1, SS1, g_kv, be_kv, kA, kB, kC);
  kv_mix_k<<<4096, 256, 0, stream>>>(hgcnb, hginb, xb, kA, kB, kC, kv_bf);
  // K|V projection in one N=512 GEMM, dual bias
  gemm_bt<146><<<dim3(256, 4, 1), 256, 0, stream>>>(kv_bf, WkaT, bk_a, bv_a,
      nullptr, nullptr, khvb, nullptr, nullptr, N_, 512, 256, 0, 0, 0);
  attn_k<<<dim3(8, 2, 128), 256, 0, stream>>>(qhb, khvb, khvb + 256, ob, 512);
  // t = x + o @ Wo_a + bo_a  [stats S2]
  gemm_bt<114><<<dim3(256, 2, 1), 256, 0, stream>>>(ob, WoaT, bo_a, nullptr,
      xb, nullptr, tbufb, S2, SS2, N_, 256, 256, 0, 0, 0);
  bn_apply_k<2><<<4096, 256, 0, stream>>>(tbufb, S2, SS2, g_attn, be_attn, nullptr, hb);
  // FFN
  gemm_bt<19><<<dim3(256, 4, 1), 256, 0, stream>>>(hb, Wf1T, bf1, nullptr,
      nullptr, nullptr, f1b, nullptr, nullptr, N_, 512, 256, 0, 0, 0);
  gemm_bt<114><<<dim3(256, 2, 1), 256, 0, stream>>>(f1b, Wf2T, bf2, nullptr,
      hb, nullptr, t2b, S3, SS3, N_, 256, 512, 0, 0, 0);
  bn_apply_k<1><<<4096, 256, 0, stream>>>(t2b, S3, SS3, g2, be2, outp, nullptr);
}

// Round 13
// 305.183 us; speedup vs baseline: 1.0360x; 1.0360x over previous
//
#include <hip/hip_runtime.h>
#include <hip/hip_bf16.h>

typedef __hip_bfloat16 bf16;
typedef __attribute__((ext_vector_type(8))) short short8;   // 8 bf16
typedef __attribute__((ext_vector_type(4))) short short4v;  // 4 bf16
typedef __attribute__((ext_vector_type(4))) float f32x4;
typedef __attribute__((ext_vector_type(4))) int i32x4;

#define N_ 32768
#define D_ 256
#define S_ 256
#define B_ 128
#define E_ 524288

static __device__ __forceinline__ f32x4 mfma16(short8 a, short8 b, f32x4 c) {
  return __builtin_amdgcn_mfma_f32_16x16x32_bf16(a, b, c, 0, 0, 0);
}
static __device__ __forceinline__ f32x4 fzero4() {
  f32x4 z; z[0] = 0.f; z[1] = 0.f; z[2] = 0.f; z[3] = 0.f; return z;
}
static __device__ __forceinline__ float bits2f(short s) {
  unsigned u = ((unsigned)(unsigned short)s) << 16;
  return __builtin_bit_cast(float, u);
}
static __device__ __forceinline__ short f2bits(float f) {
  bf16 b = __float2bfloat16(f);
  return __builtin_bit_cast(short, b);
}

#define GLOAD_LDS16(G, L) __builtin_amdgcn_global_load_lds( \
    (const __attribute__((address_space(1))) void*)(G),     \
    (__attribute__((address_space(3))) void*)(L), 16, 0, 0)

// ---------------------------------------------------------------------------
// bf16 MFMA GEMM, 128x128 tile, BK=32, double-buffered LDS (R9, no setprio).
// Flags: 1=relu, 2=bias, 4=resid f32, 8=out f32, 16=out bf16, 32=colstats,
//        64=resid bf16, 128=dual bias (biasB for cols>=256).
// ---------------------------------------------------------------------------
template<int F>
__global__ __launch_bounds__(256)
void gemm_bt(const bf16* __restrict__ A, const bf16* __restrict__ Bt,
             const float* __restrict__ bias, const float* __restrict__ biasB,
             const void* __restrict__ resid,
             float* __restrict__ Cf, bf16* __restrict__ Cb,
             float* __restrict__ Sp, float* __restrict__ SSp,
             int M, int Nc, int K, long bsA, long bsB, long bsC)
{
  __shared__ __align__(16) bf16 lA[2 * 128 * 32];
  __shared__ __align__(16) bf16 lB[2 * 128 * 32];
  __shared__ float sS[2][128], sSS[2][128];
  const int z = blockIdx.z;
  const bf16* Ab = A + (long)z * bsA;
  const bf16* Bb = Bt + (long)z * bsB;
  const int m0 = blockIdx.x * 128, n0 = blockIdx.y * 128;
  const int tid = threadIdx.x;
  const int lane = tid & 63;
  const int w = tid >> 6, wr = w >> 1, wc = w & 1;
  const int g = lane >> 4, r = lane & 15, ko = g * 8;
  const int srow = lane >> 2, skw = (lane & 3) * 8;

  f32x4 acc[4][4];
  for (int i = 0; i < 4; i++) for (int j = 0; j < 4; j++) acc[i][j] = fzero4();

  for (int i = 0; i < 2; i++) {
    const int c = w * 2 + i;
    GLOAD_LDS16(Ab + (long)(m0 + c * 16 + srow) * K + skw, lA + c * 512);
    GLOAD_LDS16(Bb + (long)(n0 + c * 16 + srow) * K + skw, lB + c * 512);
  }
  __syncthreads();

  for (int k0 = 0; k0 < K; k0 += 32) {
    const int cur = (k0 >> 5) & 1, nxt = cur ^ 1;
    if (k0 + 32 < K) {
      for (int i = 0; i < 2; i++) {
        const int c = w * 2 + i;
        GLOAD_LDS16(Ab + (long)(m0 + c * 16 + srow) * K + (k0 + 32) + skw,
                    lA + nxt * 4096 + c * 512);
        GLOAD_LDS16(Bb + (long)(n0 + c * 16 + srow) * K + (k0 + 32) + skw,
                    lB + nxt * 4096 + c * 512);
      }
    }
    short8 af[4], bfv[4];
    for (int mi = 0; mi < 4; mi++)
      af[mi] = *(const short8*)&lA[cur * 4096 + (wr * 64 + mi * 16 + r) * 32 + ko];
    for (int ni = 0; ni < 4; ni++)
      bfv[ni] = *(const short8*)&lB[cur * 4096 + (wc * 64 + ni * 16 + r) * 32 + ko];
    for (int mi = 0; mi < 4; mi++)
      for (int ni = 0; ni < 4; ni++)
        acc[mi][ni] = mfma16(af[mi], bfv[ni], acc[mi][ni]);
    __syncthreads();   // drains vmcnt(0): next buffer ready; guards cur reuse
  }

  float cs[4] = {0, 0, 0, 0}, css[4] = {0, 0, 0, 0};
  for (int mi = 0; mi < 4; mi++) for (int ni = 0; ni < 4; ni++) {
    const int row = m0 + wr * 64 + mi * 16 + g * 4;
    const int col = n0 + wc * 64 + ni * 16 + r;
    float bv = 0.0f;
    if (F & 2) {
      if ((F & 128) && col >= 256) bv = biasB[col - 256];
      else bv = bias[col];
    }
    for (int j = 0; j < 4; j++) {
      long idx = (long)(row + j) * Nc + col;
      float v = acc[mi][ni][j] + bv;
      if (F & 4)  v += ((const float*)resid)[(long)z * bsC + idx];
      if (F & 64) v += bits2f(((const short*)resid)[(long)z * bsC + idx]);
      if (F & 1)  v = fmaxf(v, 0.0f);
      if (F & 32) { cs[ni] += v; css[ni] += v * v; }
      if (F & 8)  Cf[(long)z * bsC + idx] = v;
      if (F & 16) Cb[(long)z * bsC + idx] = __float2bfloat16(v);
    }
  }
  if (F & 32) {
    for (int ni = 0; ni < 4; ni++) {
      cs[ni]  += __shfl_xor(cs[ni], 16);  cs[ni]  += __shfl_xor(cs[ni], 32);
      css[ni] += __shfl_xor(css[ni], 16); css[ni] += __shfl_xor(css[ni], 32);
    }
    if (lane < 16) {
      for (int ni = 0; ni < 4; ni++) {
        sS[wr][wc * 64 + ni * 16 + lane]  = cs[ni];
        sSS[wr][wc * 64 + ni * 16 + lane] = css[ni];
      }
    }
    __syncthreads();
    if (tid < 128) {
      atomicAdd(&Sp[n0 + tid],  sS[0][tid] + sS[1][tid]);
      atomicAdd(&SSp[n0 + tid], sSS[0][tid] + sSS[1][tid]);
    }
  }
}

// ---------------------------------------------------------------------------
// Generalized fused MLP-chain body, 512 threads / 8 waves, dbuf (R9, no
// setprio). Block = 64 rows, widths 256. Stage 1: A(global) @ B1 -> lC
// (XOR-swizzled LDS). Stages 2..NS read lC.
// EP1 bits: 1=bias 2=relu 4=resid(bf16).  EP2 bits: 1=bias 2=relu.
// ---------------------------------------------------------------------------
template<int NS, int EP1, int EP2, bool STATS>
static __device__ __forceinline__ void mlp_body(
    const bf16* __restrict__ A, const bf16* __restrict__ B1,
    const bf16* __restrict__ B2, const bf16* __restrict__ B3,
    const float* __restrict__ bEp1, const float* __restrict__ bEp2,
    const float* __restrict__ bFin, const bf16* __restrict__ resid,
    bf16* __restrict__ out, float* __restrict__ Sp, float* __restrict__ SSp,
    bf16* lA, bf16* lB, bf16* lC)
{
  char* lCc = (char*)lC;
  const int tid = threadIdx.x;          // 512 threads
  const int lane = tid & 63;
  const int w = tid >> 6;               // 8 waves: mh = w>>2, nq = w&3
  const int mh = w >> 2, nq = w & 3;
  const int g = lane >> 4, r = lane & 15, ko = g * 8;

  f32x4 acc[2][4];
  for (int i = 0; i < 2; i++) for (int j = 0; j < 4; j++) acc[i][j] = fzero4();

  // ---- stage 1: acc = A @ B1 (dbuf) ----
  if (tid < 256)
    GLOAD_LDS16(A + (long)(tid >> 2) * 256 + (tid & 3) * 8, lA + w * 512);
  GLOAD_LDS16(B1 + (long)(tid >> 2) * 256 + (tid & 3) * 8, lB + w * 512);
  GLOAD_LDS16(B1 + (long)((tid + 512) >> 2) * 256 + ((tid + 512) & 3) * 8,
              lB + w * 512 + 4096);
  __syncthreads();
  for (int k0 = 0; k0 < 256; k0 += 32) {
    const int cur = (k0 >> 5) & 1, nxt = cur ^ 1;
    if (k0 + 32 < 256) {
      if (tid < 256)
        GLOAD_LDS16(A + (long)(tid >> 2) * 256 + (k0 + 32) + (tid & 3) * 8,
                    lA + nxt * 2048 + w * 512);
      GLOAD_LDS16(B1 + (long)(tid >> 2) * 256 + (k0 + 32) + (tid & 3) * 8,
                  lB + nxt * 8192 + w * 512);
      GLOAD_LDS16(B1 + (long)((tid + 512) >> 2) * 256 + (k0 + 32) + ((tid + 512) & 3) * 8,
                  lB + nxt * 8192 + w * 512 + 4096);
    }
    short8 af[2], bfv[4];
    for (int mi = 0; mi < 2; mi++)
      af[mi] = *(const short8*)&lA[cur * 2048 + (mh * 32 + mi * 16 + r) * 32 + ko];
    for (int ni = 0; ni < 4; ni++)
      bfv[ni] = *(const short8*)&lB[cur * 8192 + (nq * 64 + ni * 16 + r) * 32 + ko];
    for (int mi = 0; mi < 2; mi++)
      for (int ni = 0; ni < 4; ni++)
        acc[mi][ni] = mfma16(af[mi], bfv[ni], acc[mi][ni]);
    __syncthreads();
  }
  // epilogue 1 -> lC (swizzled)
  for (int mi = 0; mi < 2; mi++) for (int ni = 0; ni < 4; ni++) {
    const int col = nq * 64 + ni * 16 + r;
    const float bv = (EP1 & 1) ? bEp1[col] : 0.0f;
    for (int j = 0; j < 4; j++) {
      const int row = mh * 32 + mi * 16 + g * 4 + j;
      float v = acc[mi][ni][j] + bv;
      if (EP1 & 4) v += bits2f(__builtin_bit_cast(short, resid[(long)row * 256 + col]));
      if (EP1 & 2) v = fmaxf(v, 0.0f);
      *(short*)(lCc + ((row * 512 + col * 2) ^ ((row & 7) << 4))) = f2bits(v);
    }
  }
  __syncthreads();

  // ---- stages 2..NS: acc = lC @ Bs (dbuf lB) ----
  for (int s = 2; s <= NS; s++) {
    const bf16* Bs = (s == 2) ? B2 : B3;
    for (int i = 0; i < 2; i++) for (int j = 0; j < 4; j++) acc[i][j] = fzero4();
    GLOAD_LDS16(Bs + (long)(tid >> 2) * 256 + (tid & 3) * 8, lB + w * 512);
    GLOAD_LDS16(Bs + (long)((tid + 512) >> 2) * 256 + ((tid + 512) & 3) * 8,
                lB + w * 512 + 4096);
    __syncthreads();
    for (int k0 = 0; k0 < 256; k0 += 32) {
      const int cur = (k0 >> 5) & 1, nxt = cur ^ 1;
      if (k0 + 32 < 256) {
        GLOAD_LDS16(Bs + (long)(tid >> 2) * 256 + (k0 + 32) + (tid & 3) * 8,
                    lB + nxt * 8192 + w * 512);
        GLOAD_LDS16(Bs + (long)((tid + 512) >> 2) * 256 + (k0 + 32) + ((tid + 512) & 3) * 8,
                    lB + nxt * 8192 + w * 512 + 4096);
      }
      short8 af[2], bfv[4];
      for (int mi = 0; mi < 2; mi++) {
        const int row = mh * 32 + mi * 16 + r;
        af[mi] = *(const short8*)(lCc +
                  ((row * 512 + (k0 + ko) * 2) ^ ((row & 7) << 4)));
      }
      for (int ni = 0; ni < 4; ni++)
        bfv[ni] = *(const short8*)&lB[cur * 8192 + (nq * 64 + ni * 16 + r) * 32 + ko];
      for (int mi = 0; mi < 2; mi++)
        for (int ni = 0; ni < 4; ni++)
          acc[mi][ni] = mfma16(af[mi], bfv[ni], acc[mi][ni]);
      __syncthreads();
    }
    if (s < NS) {
      for (int mi = 0; mi < 2; mi++) for (int ni = 0; ni < 4; ni++) {
        const int col = nq * 64 + ni * 16 + r;
        const float bv = (EP2 & 1) ? bEp2[col] : 0.0f;
        for (int j = 0; j < 4; j++) {
          const int row = mh * 32 + mi * 16 + g * 4 + j;
          float v = acc[mi][ni][j] + bv;
          if (EP2 & 2) v = fmaxf(v, 0.0f);
          *(short*)(lCc + ((row * 512 + col * 2) ^ ((row & 7) << 4))) = f2bits(v);
        }
      }
      __syncthreads();
    }
  }

  // ---- final epilogue ----
  float cs[4] = {0, 0, 0, 0}, css[4] = {0, 0, 0, 0};
  for (int mi = 0; mi < 2; mi++) for (int ni = 0; ni < 4; ni++) {
    const int col = nq * 64 + ni * 16 + r;
    const float bv = bFin[col];
    for (int j = 0; j < 4; j++) {
      const int row = mh * 32 + mi * 16 + g * 4 + j;
      float v = acc[mi][ni][j] + bv;
      if (STATS) { cs[ni] += v; css[ni] += v * v; }
      out[(long)row * 256 + col] = __float2bfloat16(v);
    }
  }
  if (STATS) {
    for (int ni = 0; ni < 4; ni++) {
      cs[ni]  += __shfl_xor(cs[ni], 16);  cs[ni]  += __shfl_xor(cs[ni], 32);
      css[ni] += __shfl_xor(css[ni], 16); css[ni] += __shfl_xor(css[ni], 32);
    }
    __syncthreads();
    float* sS = (float*)lC;
    if (lane < 16) {
      for (int ni = 0; ni < 4; ni++) {
        sS[mh * 256 + nq * 64 + ni * 16 + lane] = cs[ni];
        sS[512 + mh * 256 + nq * 64 + ni * 16 + lane] = css[ni];
      }
    }
    __syncthreads();
    if (tid < 256) {
      atomicAdd(&Sp[tid],  sS[tid] + sS[256 + tid]);
      atomicAdd(&SSp[tid], sS[512 + tid] + sS[768 + tid]);
    }
  }
}

// One launch: GCN expert (blocks 0-511), GIN expert (512-1023), Q-chain
// (1024-1535).
__global__ __launch_bounds__(512)
void fused3_k(const bf16* __restrict__ adjGCNb, const bf16* __restrict__ adjGINb,
              const bf16* __restrict__ xT, const bf16* __restrict__ xb,
              const bf16* __restrict__ WgcnT, const bf16* __restrict__ Wgin1T,
              const bf16* __restrict__ Wgin2T, const bf16* __restrict__ Wq1T,
              const bf16* __restrict__ Wq2T, const bf16* __restrict__ WqaT,
              const float* __restrict__ b_gcn, const float* __restrict__ b_gin1,
              const float* __restrict__ b_gin2, const float* __restrict__ bq1,
              const float* __restrict__ bq2, const float* __restrict__ bq_a,
              bf16* __restrict__ hgcnb, bf16* __restrict__ hginb,
              bf16* __restrict__ qhb,
              float* __restrict__ S0, float* __restrict__ SS0,
              float* __restrict__ S1, float* __restrict__ SS1)
{
  __shared__ __align__(16) bf16 lA[2 * 64 * 32];     // 8 KB dbuf
  __shared__ __align__(16) bf16 lB[2 * 256 * 32];    // 32 KB dbuf
  __shared__ __align__(16) bf16 lC[64 * 256];        // 32 KB
  const int bid = blockIdx.x;
  if (bid < 512) {
    const long g = bid >> 2;
    mlp_body<2, 0, 0, true>(adjGCNb + (long)bid * 16384, xT + g * 65536,
        WgcnT, nullptr, nullptr, nullptr, b_gcn, nullptr,
        hgcnb + (long)bid * 16384, S0, SS0, lA, lB, lC);
  } else if (bid < 1024) {
    const int sub = bid - 512;
    const long g = sub >> 2;
    mlp_body<3, 4, 3, true>(adjGINb + (long)sub * 16384, xT + g * 65536,
        Wgin1T, Wgin2T, nullptr, b_gin1, b_gin2, xb + (long)sub * 16384,
        hginb + (long)sub * 16384, S1, SS1, lA, lB, lC);
  } else {
    const int sub = bid - 1024;
    mlp_body<3, 3, 1, false>(xb + (long)sub * 16384, Wq1T, Wq2T, WqaT,
        bq1, bq2, bq_a, nullptr, qhb + (long)sub * 16384, nullptr, nullptr,
        lA, lB, lC);
  }
}

// ---------------------------------------------------------------------------
// Fused attention, swapped-QK^T (exact R9 version: q-half grid, paired-u32
// V-staging, setprio around MFMA clusters).
// ---------------------------------------------------------------------------
__global__ __launch_bounds__(256, 2)
void attn_k(const bf16* __restrict__ qh, const bf16* __restrict__ kh,
            const bf16* __restrict__ vh, bf16* __restrict__ ob, int ks)
{
  const int h = blockIdx.x, qhf = blockIdx.y, b = blockIdx.z;
  const int tid = threadIdx.x, lane = tid & 63, w = tid >> 6;
  const int g = lane >> 4, r = lane & 15, ko = g * 8;
  __shared__ __align__(16) bf16 lK[256 * 32];
  __shared__ __align__(16) bf16 lV[32 * 256];
  char* lKc = (char*)lK;
  char* lVc = (char*)lV;

  for (int i = 0; i < 4; i++) {
    int c = tid + i * 256;
    int row = c >> 2, p4 = c & 3;
    short8 v = *(const short8*)(kh + (long)(b * 256 + row) * ks + h * 32 + p4 * 8);
    *(short8*)(lKc + ((row * 64 + p4 * 16) ^ ((row & 7) << 4))) = v;
  }
  for (int i = 0; i < 2; i++) {
    int c = tid + i * 256;
    int sp = c >> 2, part = c & 3;
    const bf16* vp = vh + (long)(b * 256 + 2 * sp) * ks + h * 32 + part * 8;
    short8 va = *(const short8*)(vp);
    short8 vb = *(const short8*)(vp + ks);
    #pragma unroll
    for (int j = 0; j < 8; j++) {
      int dh = part * 8 + j;
      int sw = ((dh & 7) ^ ((dh >> 3) << 1)) & 7;
      unsigned wrd = ((unsigned)(unsigned short)vb[j] << 16) |
                     (unsigned)(unsigned short)va[j];
      *(unsigned*)(lVc + ((dh * 512 + sp * 4) ^ (sw << 4))) = wrd;
    }
  }
  __syncthreads();

  const float c1 = 0.17677669529663687f * 1.4426950408889634f;
  const int idx0 = (((lane >> 4) & 1) * 32 + r) * 4;
  const int idx1 = idx0 + 64;
  const bool selhi = lane >= 32;

  for (int mc = 0; mc < 2; mc++) {
    const long qbase = (long)b * 256 + qhf * 128 + w * 32 + mc * 16;
    short8 qf = *(const short8*)(qh + (qbase + r) * 256 + h * 32 + ko);
    f32x4 sc[16];
    __builtin_amdgcn_s_setprio(1);
    #pragma unroll
    for (int nc = 0; nc < 16; nc++) {
      int row = nc * 16 + r;
      short8 kf = *(const short8*)(lKc + ((row * 64 + g * 16) ^ ((r & 7) << 4)));
      sc[nc] = mfma16(kf, qf, fzero4());
    }
    __builtin_amdgcn_s_setprio(0);
    f32x4 m4 = sc[0];
    #pragma unroll
    for (int nc = 1; nc < 16; nc++)
      for (int j = 0; j < 4; j++) m4[j] = fmaxf(m4[j], sc[nc][j]);
    float mx = fmaxf(fmaxf(m4[0], m4[1]), fmaxf(m4[2], m4[3]));
    mx = fmaxf(mx, __shfl_xor(mx, 16));
    mx = fmaxf(mx, __shfl_xor(mx, 32));
    const float mxc = mx * c1;
    f32x4 s4 = fzero4();
    #pragma unroll
    for (int nc = 0; nc < 16; nc++)
      for (int j = 0; j < 4; j++) {
        float p = exp2f(fmaf(sc[nc][j], c1, -mxc));
        sc[nc][j] = p; s4[j] += p;
      }
    float sum = s4[0] + s4[1] + s4[2] + s4[3];
    sum += __shfl_xor(sum, 16);
    sum += __shfl_xor(sum, 32);
    const float invs = 1.0f / sum;
    f32x4 oa[2]; oa[0] = fzero4(); oa[1] = fzero4();
    __builtin_amdgcn_s_setprio(1);
    #pragma unroll
    for (int kc = 0; kc < 8; kc++) {
      int pkA0, pkA1, pkB0, pkB1;
      {
        const f32x4 pa = sc[2 * kc], pb = sc[2 * kc + 1];
        unsigned a0 = (unsigned short)f2bits(pa[0] * invs);
        unsigned a1 = (unsigned short)f2bits(pa[1] * invs);
        unsigned a2 = (unsigned short)f2bits(pa[2] * invs);
        unsigned a3 = (unsigned short)f2bits(pa[3] * invs);
        unsigned b0 = (unsigned short)f2bits(pb[0] * invs);
        unsigned b1 = (unsigned short)f2bits(pb[1] * invs);
        unsigned b2 = (unsigned short)f2bits(pb[2] * invs);
        unsigned b3 = (unsigned short)f2bits(pb[3] * invs);
        pkA0 = (int)((a1 << 16) | a0);
        pkA1 = (int)((a3 << 16) | a2);
        pkB0 = (int)((b1 << 16) | b0);
        pkB1 = (int)((b3 << 16) | b2);
      }
      int A0 = __builtin_amdgcn_ds_bpermute(idx0, pkA0);
      int A1 = __builtin_amdgcn_ds_bpermute(idx0, pkA1);
      int B0 = __builtin_amdgcn_ds_bpermute(idx0, pkB0);
      int B1 = __builtin_amdgcn_ds_bpermute(idx0, pkB1);
      int C0 = __builtin_amdgcn_ds_bpermute(idx1, pkA0);
      int C1 = __builtin_amdgcn_ds_bpermute(idx1, pkA1);
      int D0 = __builtin_amdgcn_ds_bpermute(idx1, pkB0);
      int D1 = __builtin_amdgcn_ds_bpermute(idx1, pkB1);
      i32x4 av;
      av[0] = selhi ? B0 : A0;
      av[1] = selhi ? B1 : A1;
      av[2] = selhi ? D0 : C0;
      av[3] = selhi ? D1 : C1;
      short8 af = __builtin_bit_cast(short8, av);
      #pragma unroll
      for (int n = 0; n < 2; n++) {
        int dh = n * 16 + r;
        int sw = ((dh & 7) ^ ((dh >> 3) << 1)) & 7;
        short8 bv = *(const short8*)(lVc + ((dh * 512 + kc * 64 + g * 16) ^ (sw << 4)));
        oa[n] = mfma16(af, bv, oa[n]);
      }
    }
    __builtin_amdgcn_s_setprio(0);
    #pragma unroll
    for (int n = 0; n < 2; n++)
      for (int j = 0; j < 4; j++)
        ob[(qbase + g * 4 + j) * 256 + h * 32 + n * 16 + r] =
          __float2bfloat16(oa[n][j]);
  }
}

// ---------------------------------------------------------------------------
// Merged preamble: blocks 0-831 weight transposes; 832-9023 xprep (x -> xb +
// per-graph xT); 9024-11071 edge_cnt. All independent.
// ---------------------------------------------------------------------------
__global__ __launch_bounds__(256)
void prep_k(const float* w0, const float* w1, const float* w2, const float* w3,
            const float* w4, const float* w5, const float* w6, const float* w7,
            const float* w8, const float* wf1, const float* wf2,
            bf16* __restrict__ wT,
            const float* __restrict__ x, bf16* __restrict__ xb,
            bf16* __restrict__ xT,
            const int* __restrict__ ei, unsigned* __restrict__ cnt)
{
  __shared__ float tile[32][33];
  const int bid = blockIdx.x;
  const int tid = threadIdx.x;
  const int tx = tid & 31, ty = tid >> 5;

  if (bid < 832) {                 // ---- weight transposes ----
    const float* srcs[9] = {w0, w1, w2, w3, w4, w5, w6, w7, w8};
    const float* in; bf16* out; int in_rs, out_rs, bx, by;
    if (bid < 576) {
      int wi = bid >> 6, t = bid & 63;
      in = srcs[wi]; out = wT + (long)wi * 65536;
      in_rs = 256; out_rs = 256; bx = t & 7; by = t >> 3;
    } else if (bid < 704) {
      int t = bid - 576;
      in = wf1; out = wT + 589824;
      in_rs = 512; out_rs = 256; bx = t & 15; by = t >> 4;
    } else {
      int t = bid - 704;
      in = wf2; out = wT + 720896;
      in_rs = 256; out_rs = 512; bx = t & 7; by = t >> 3;
    }
    const int c = bx * 32 + tx;
    const int rb = by * 32;
    for (int i = 0; i < 4; i++)
      tile[ty + i * 8][tx] = in[(long)(rb + ty + i * 8) * in_rs + c];
    __syncthreads();
    const int oc = rb + tx;
    const int orb = bx * 32;
    for (int i = 0; i < 4; i++)
      out[(long)(orb + ty + i * 8) * out_rs + oc] =
        __float2bfloat16(tile[tx][ty + i * 8]);
  } else if (bid < 9024) {         // ---- xprep ----
    const int b2 = bid - 832;
    const int z = b2 >> 6, bx = b2 & 7, by = (b2 >> 3) & 7;
    const long ioff = (long)z * 65536;
    const int c = bx * 32 + tx;
    const int rb = by * 32;
    for (int i = 0; i < 4; i++) {
      float v = x[ioff + (long)(rb + ty + i * 8) * 256 + c];
      tile[ty + i * 8][tx] = v;
      xb[ioff + (long)(rb + ty + i * 8) * 256 + c] = __float2bfloat16(v);
    }
    __syncthreads();
    const int oc = rb + tx;
    const int orb = bx * 32;
    for (int i = 0; i < 4; i++)
      xT[ioff + (long)(orb + ty + i * 8) * 256 + oc] =
        __float2bfloat16(tile[tx][ty + i * 8]);
  } else {                         // ---- edge_cnt ----
    int e = (bid - 9024) * 256 + tid;
    int src = ei[e], dst = ei[E_ + e];
    long idx = ((long)(src >> 8) * 256 + (dst & 255)) * 256 + (src & 255);
    atomicAdd(&cnt[idx >> 2], 1u << ((idx & 3) * 8));
  }
}

// ---------------------------------------------------------------------------
// deg from row-sums of u8 cnt (+1 self loop) -> dinv. 16 lanes per row.
// Full-GPU grids (R12: reverted from the 128-block graph_prep_k, which left
// half the CUs idle and ran ~80 serial iterations per block).
// ---------------------------------------------------------------------------
__global__ __launch_bounds__(256)
void deg_k(const unsigned* __restrict__ cnt, float* __restrict__ dinv)
{
  int rid = blockIdx.x * 16 + (threadIdx.x >> 4);
  int l16 = threadIdx.x & 15;
  uint4 v = ((const uint4*)(cnt + (long)rid * 64))[l16];
  unsigned s = 0;
  s += (v.x & 0xFF) + ((v.x >> 8) & 0xFF) + ((v.x >> 16) & 0xFF) + (v.x >> 24);
  s += (v.y & 0xFF) + ((v.y >> 8) & 0xFF) + ((v.y >> 16) & 0xFF) + (v.y >> 24);
  s += (v.z & 0xFF) + ((v.z >> 8) & 0xFF) + ((v.z >> 16) & 0xFF) + (v.z >> 24);
  s += (v.w & 0xFF) + ((v.w >> 8) & 0xFF) + ((v.w >> 16) & 0xFF) + (v.w >> 24);
  s += __shfl_xor(s, 1); s += __shfl_xor(s, 2);
  s += __shfl_xor(s, 4); s += __shfl_xor(s, 8);
  if (l16 == 0) dinv[rid] = rsqrtf((float)s + 1.0f);
}

// derive both bf16 adjacencies from u8 counts + dinv (+ GCN self-loop)
__global__ __launch_bounds__(256)
void adj_derive_k(const unsigned* __restrict__ cnt, const float* __restrict__ dinv,
                  bf16* __restrict__ gin, bf16* __restrict__ gcn)
{
  long wi = (long)blockIdx.x * 256 + threadIdx.x;
  unsigned cw = cnt[wi];
  long i = wi * 4;
  float cv[4] = {(float)(cw & 0xFF), (float)((cw >> 8) & 0xFF),
                 (float)((cw >> 16) & 0xFF), (float)(cw >> 24)};
  long row = i >> 8;
  int g = (int)(row >> 8), dst = (int)(row & 255);
  int src0 = (int)(i & 255);
  float dd = dinv[row];
  const float* ds = dinv + (long)g * 256 + src0;
  short4v oi, oc;
  for (int j = 0; j < 4; j++) {
    float gv = cv[j] * dd * ds[j];
    if (src0 + j == dst) gv += dd * dd;
    oi[j] = f2bits(cv[j]);
    oc[j] = f2bits(gv);
  }
  *(short4v*)(gin + i) = oi;
  *(short4v*)(gcn + i) = oc;
}

// BN(e0),BN(e1) stats -> global mean/std(ddof=1) -> mix coefficients
__global__ __launch_bounds__(256)
void expert_stats_k(const float* __restrict__ S0, const float* __restrict__ SS0,
                    const float* __restrict__ S1, const float* __restrict__ SS1,
                    const float* __restrict__ gkv, const float* __restrict__ bkv,
                    float* __restrict__ kA, float* __restrict__ kB,
                    float* __restrict__ kC)
{
  const int d = threadIdx.x;
  const float invN = 1.0f / 32768.0f;
  float m0 = S0[d] * invN, v0 = SS0[d] * invN - m0 * m0;
  float a0 = gkv[d] * rsqrtf(v0 + 1e-5f), c0 = bkv[d] - m0 * a0;
  float m1 = S1[d] * invN, v1 = SS1[d] * invN - m1 * m1;
  float a1 = gkv[d] * rsqrtf(v1 + 1e-5f), c1 = bkv[d] - m1 * a1;
  float gsum = a0 * S0[d] + 32768.0f * c0 + a1 * S1[d] + 32768.0f * c1;
  float gss  = a0 * a0 * SS0[d] + 2.0f * a0 * c0 * S0[d] + 32768.0f * c0 * c0
             + a1 * a1 * SS1[d] + 2.0f * a1 * c1 * S1[d] + 32768.0f * c1 * c1;
  __shared__ float r1[256], r2[256];
  r1[d] = gsum; r2[d] = gss;
  __syncthreads();
  for (int s = 128; s > 0; s >>= 1) {
    if (d < s) { r1[d] += r1[d + s]; r2[d] += r2[d + s]; }
    __syncthreads();
  }
  const float cntall = 16777216.0f;  // 2*N*D
  float tg = r1[0], tss = r2[0];
  float gm = tg / cntall;
  float var = (tss - tg * tg / cntall) / (cntall - 1.0f);
  float gs = sqrtf(fmaxf(var, 0.f)) + 1e-8f;
  kA[d] = 0.5f * a0 / gs;
  kB[d] = 0.5f * a1 / gs;
  kC[d] = 0.5f * (c0 + c1 - 2.0f * gm) / gs;
}

__global__ __launch_bounds__(256)
void kv_mix_k(const bf16* __restrict__ hgcn, const bf16* __restrict__ hgin,
              const bf16* __restrict__ xb, const float* __restrict__ kA,
              const float* __restrict__ kB, const float* __restrict__ kC,
              bf16* __restrict__ kv)
{
  long i = ((long)blockIdx.x * 256 + threadIdx.x) * 8;
  int d0 = (int)(i & 255);
  short8 a = *(const short8*)(hgcn + i);
  short8 b = *(const short8*)(hgin + i);
  short8 c = *(const short8*)(xb + i);
  short8 o;
  for (int j = 0; j < 8; j++) {
    int d = d0 + j;
    float v = kA[d] * bits2f(a[j]) + kB[d] * bits2f(b[j]) + kC[d] + 0.1f * bits2f(c[j]);
    o[j] = f2bits(v);
  }
  *(short8*)(kv + i) = o;
}

// MODE: 1 = write f32, 2 = write bf16
template<int MODE>
__global__ __launch_bounds__(256)
void bn_apply_k(const bf16* __restrict__ in, const float* __restrict__ S,
                const float* __restrict__ SSq, const float* __restrict__ gg,
                const float* __restrict__ bb, float* __restrict__ outf,
                bf16* __restrict__ outb)
{
  long i = ((long)blockIdx.x * 256 + threadIdx.x) * 8;
  int d0 = (int)(i & 255);
  short8 v = *(const short8*)(in + i);
  const float invN = 1.0f / 32768.0f;
  float4 o0, o1; short8 o8;
  for (int j = 0; j < 8; j++) {
    int d = d0 + j;
    float m = S[d] * invN;
    float var = SSq[d] * invN - m * m;
    float a = gg[d] * rsqrtf(var + 1e-5f);
    float c = bb[d] - m * a;
    float o = a * bits2f(v[j]) + c;
    if (MODE & 1) { if (j < 4) (&o0.x)[j] = o; else (&o1.x)[j - 4] = o; }
    if (MODE & 2) o8[j] = f2bits(o);
  }
  if (MODE & 1) { *(float4*)(outf + i) = o0; *(float4*)(outf + i + 4) = o1; }
  if (MODE & 2) *(short8*)(outb + i) = o8;
}

// ---------------------------------------------------------------------------
// Workspace layout (bytes). qhb lives in the dead counts slot (16.7MB);
// tbufb/t2b reuse it after attn.
// ---------------------------------------------------------------------------
static constexpr size_t OFF_S0 = 0, OFF_SS0 = 1024, OFF_S1 = 2048, OFF_SS1 = 3072;
static constexpr size_t OFF_S2 = 4096, OFF_SS2 = 5120, OFF_S3 = 6144, OFF_SS3 = 7168;
static constexpr size_t OFF_KA = 8192, OFF_KB = 9216, OFF_KC = 10240;
static constexpr size_t OFF_CNT = 16384;                       // u8 counts -> qhb -> tbufb
static constexpr size_t CNT_BYTES = (size_t)B_ * S_ * S_;      // 8388608
static constexpr size_t ZERO_BYTES = OFF_CNT + CNT_BYTES;
static constexpr size_t OFF_DINV = OFF_CNT + (size_t)B_ * S_ * S_ * 2;
static constexpr size_t OFF_W = OFF_DINV + 131072;
static constexpr size_t NDB2 = (size_t)N_ * D_ * 2;            // 16777216
static constexpr size_t OFF_ADJGINB = OFF_W + 1703936;   // adjGIN -> f1b(lo)
static constexpr size_t OFF_ADJGCNB = OFF_ADJGINB + NDB2; // adjGCN -> f1b(hi)
static constexpr size_t OFF_XB   = OFF_ADJGCNB + NDB2;    // xb -> hb
static constexpr size_t OFF_XT   = OFF_XB + NDB2;         // xT
static constexpr size_t OFF_AGG  = OFF_XT + NDB2;         // khvb(lo)
static constexpr size_t OFF_GIN  = OFF_AGG + NDB2;        // khvb(hi)
static constexpr size_t OFF_KV   = OFF_GIN + NDB2;        // kv
static constexpr size_t OFF_HGCN = OFF_KV + NDB2;         // hgcn
static constexpr size_t OFF_HGIN = OFF_HGCN + NDB2;       // hgin -> ob

extern "C" void kernel_launch(void* const* d_in, const int* in_sizes, int n_in,
                              void* d_out, int out_size, void* d_ws, size_t ws_size,
                              hipStream_t stream)
{
  (void)in_sizes; (void)n_in; (void)out_size; (void)ws_size;
  const float* x      = (const float*)d_in[0];
  const int*   ei     = (const int*)d_in[1];
  const float* W_gcn  = (const float*)d_in[2];
  const float* b_gcn  = (const float*)d_in[3];
  const float* W_gin1 = (const float*)d_in[4];
  const float* b_gin1 = (const float*)d_in[5];
  const float* W_gin2 = (const float*)d_in[6];
  const float* b_gin2 = (const float*)d_in[7];
  const float* g_kv   = (const float*)d_in[8];
  const float* be_kv  = (const float*)d_in[9];
  const float* Wq1    = (const float*)d_in[10];
  const float* bq1    = (const float*)d_in[11];
  const float* Wq2    = (const float*)d_in[12];
  const float* bq2    = (const float*)d_in[13];
  const float* Wq_a   = (const float*)d_in[14];
  const float* bq_a   = (const float*)d_in[15];
  const float* Wk_a   = (const float*)d_in[16];
  const float* bk_a   = (const float*)d_in[17];
  const float* Wv_a   = (const float*)d_in[18];
  const float* bv_a   = (const float*)d_in[19];
  const float* Wo_a   = (const float*)d_in[20];
  const float* bo_a   = (const float*)d_in[21];
  const float* g_attn = (const float*)d_in[22];
  const float* be_attn= (const float*)d_in[23];
  const float* Wf1    = (const float*)d_in[24];
  const float* bf1    = (const float*)d_in[25];
  const float* Wf2    = (const float*)d_in[26];
  const float* bf2    = (const float*)d_in[27];
  const float* g2     = (const float*)d_in[28];
  const float* be2    = (const float*)d_in[29];

  char* ws = (char*)d_ws;
  float* S0  = (float*)(ws + OFF_S0);  float* SS0 = (float*)(ws + OFF_SS0);
  float* S1  = (float*)(ws + OFF_S1);  float* SS1 = (float*)(ws + OFF_SS1);
  float* S2  = (float*)(ws + OFF_S2);  float* SS2 = (float*)(ws + OFF_SS2);
  float* S3  = (float*)(ws + OFF_S3);  float* SS3 = (float*)(ws + OFF_SS3);
  float* kA  = (float*)(ws + OFF_KA);  float* kB  = (float*)(ws + OFF_KB);
  float* kC  = (float*)(ws + OFF_KC);
  unsigned* cntA = (unsigned*)(ws + OFF_CNT);
  float* dinv = (float*)(ws + OFF_DINV);
  bf16* wT = (bf16*)(ws + OFF_W);
  bf16 *WgcnT = wT,            *Wgin1T = wT + 65536,  *Wgin2T = wT + 131072;
  bf16 *Wq1T  = wT + 196608,   *Wq2T   = wT + 262144, *WqaT   = wT + 327680;
  bf16 *WkaT  = wT + 393216,   *WoaT   = wT + 524288;
  bf16 *Wf1T  = wT + 589824,   *Wf2T   = wT + 720896;
  bf16* adjGINb = (bf16*)(ws + OFF_ADJGINB);
  bf16* adjGCNb = (bf16*)(ws + OFF_ADJGCNB);
  bf16* xb    = (bf16*)(ws + OFF_XB);
  bf16* xT    = (bf16*)(ws + OFF_XT);
  bf16* kv_bf = (bf16*)(ws + OFF_KV);
  bf16* hgcnb = (bf16*)(ws + OFF_HGCN);
  bf16* hginb = (bf16*)(ws + OFF_HGIN);
  // lifetime-disjoint aliases
  bf16* qhb    = (bf16*)(ws + OFF_CNT);    // counts dead after adj_derive
  bf16* khvb   = (bf16*)(ws + OFF_AGG);    // [N][512], spans AGG+GIN
  bf16* ob     = hginb;                    // after kv_mix consumed hgin
  bf16* tbufb  = (bf16*)(ws + OFF_CNT);    // after attn consumed qhb
  bf16* hb     = xb;                       // after o-GEMM consumed xb resid
  bf16* f1b    = adjGINb;                  // spans ADJGIN+ADJGCN (33.5MB)
  bf16* t2b    = (bf16*)(ws + OFF_CNT);    // after bn_apply<2> consumed tbufb
  float* outp  = (float*)d_out;

  hipMemsetAsync(d_ws, 0, ZERO_BYTES, stream);

  // merged preamble: weights + x-prep + edge counting, one launch
  prep_k<<<11072, 256, 0, stream>>>(W_gcn, W_gin1, W_gin2, Wq1, Wq2,
      Wq_a, Wk_a, Wv_a, Wo_a, Wf1, Wf2, wT, x, xb, xT, ei, cntA);
  // graph derive: full-GPU grids (R12 revert of the 128-block merge)
  deg_k<<<2048, 256, 0, stream>>>(cntA, dinv);
  adj_derive_k<<<8192, 256, 0, stream>>>(cntA, dinv, adjGINb, adjGCNb);
  // GCN expert + GIN expert + Q-chain in ONE launch (512-thread, dbuf)
  fused3_k<<<1536, 512, 0, stream>>>(adjGCNb, adjGINb, xT, xb,
      WgcnT, Wgin1T, Wgin2T, Wq1T, Wq2T, WqaT,
      b_gcn, b_gin1, b_gin2, bq1, bq2, bq_a,
      hgcnb, hginb, qhb, S0, SS0, S1, SS1);
  expert_stats_k<<<1, 256, 0, stream>>>(S0, SS0, S1, SS1, g_kv, be_kv, kA, kB, kC);
  kv_mix_k<<<4096, 256, 0, stream>>>(hgcnb, hginb, xb, kA, kB, kC, kv_bf);
  // K|V projection in one N=512 GEMM, dual bias
  gemm_bt<146><<<dim3(256, 4, 1), 256, 0, stream>>>(kv_bf, WkaT, bk_a, bv_a,
      nullptr, nullptr, khvb, nullptr, nullptr, N_, 512, 256, 0, 0, 0);
  attn_k<<<dim3(8, 2, 128), 256, 0, stream>>>(qhb, khvb, khvb + 256, ob, 512);
  // t = x + o @ Wo_a + bo_a  [stats S2]
  gemm_bt<114><<<dim3(256, 2, 1), 256, 0, stream>>>(ob, WoaT, bo_a, nullptr,
      xb, nullptr, tbufb, S2, SS2, N_, 256, 256, 0, 0, 0);
  bn_apply_k<2><<<4096, 256, 0, stream>>>(tbufb, S2, SS2, g_attn, be_attn, nullptr, hb);
  // FFN
  gemm_bt<19><<<dim3(256, 4, 1), 256, 0, stream>>>(hb, Wf1T, bf1, nullptr,
      nullptr, nullptr, f1b, nullptr, nullptr, N_, 512, 256, 0, 0, 0);
  gemm_bt<114><<<dim3(256, 2, 1), 256, 0, stream>>>(f1b, Wf2T, bf2, nullptr,
      hb, nullptr, t2b, S3, SS3, N_, 256, 512, 0, 0, 0);
  bn_apply_k<1><<<4096, 256, 0, stream>>>(t2b, S3, SS3, g2, be2, outp, nullptr);
}